// Round 3
// baseline (2582.708 us; speedup 1.0000x reference)
//
#include <hip/hip_runtime.h>
#include <stdint.h>

typedef __bf16 bf16;
typedef __bf16 bf16x8 __attribute__((ext_vector_type(8)));
typedef float f32x4 __attribute__((ext_vector_type(4)));

#define NN 30000
#define NE 300000
#define NG 128
#define DD 128

// ---------------------------------------------------------------------------
// f32-accurate GEMM via 3-term bf16 split: a*b ~= ah*bh + ah*bl + al*bh.
// ah = bf16(a) (RNE), al = bf16(a - ah) (Sterbenz-exact residual, ~2^-17 total).
// Weights pre-split+transposed to [N,K] hi/lo bf16. A split on the fly.
// ---------------------------------------------------------------------------

// Wide GEMM: one block = full 128(M) x 256(N) tile -> layer can run in place.
// 512 threads = 8 waves in 2x4. MODE 0: plain A[M,K] f32.
// MODE 1: edge concat [nodes[row]|nodes[col]|eattr|u[batch[row]]] (K=512)
// MODE 2: node concat [nodes|agg|u[batch]] (K=384)
template <int MODE>
__global__ __launch_bounds__(512) void gemm_wide(
    const float* __restrict__ A, const bf16* __restrict__ Bh,
    const bf16* __restrict__ Bl, const float* __restrict__ bias,
    float* __restrict__ C, int M, int K, int do_relu,
    const float* __restrict__ s0, const float* __restrict__ s1,
    const float* __restrict__ s2, const int* __restrict__ i0,
    const int* __restrict__ i1, const int* __restrict__ i2) {
  __shared__ bf16 Ash[128 * 32];
  __shared__ bf16 Asl[128 * 32];
  __shared__ bf16 Bsh[256 * 32];
  __shared__ bf16 Bsl[256 * 32];
  const int tid = threadIdx.x;
  const int w = tid >> 6, lane = tid & 63;
  const int wm = w >> 2, wn = w & 3;  // 2 x 4 waves over 128 x 256
  const int m0 = blockIdx.x * 128;
  const int ar = tid >> 2;        // 0..127: A row / B row pair
  const int k8 = (tid & 3) * 8;   // 0,8,16,24 within 32-wide k-slab

  int gm = m0 + ar;
  if (gm > M - 1) gm = M - 1;  // clamp partial tile; stores guarded below
  int rv = 0, cv = 0, bv = 0;
  if (MODE == 1) {
    rv = i0[gm];
    cv = i1[gm];
    bv = i2[rv];
  } else if (MODE == 2) {
    bv = i2[gm];
  }

  f32x4 acc[4][4];
#pragma unroll
  for (int a = 0; a < 4; ++a)
#pragma unroll
    for (int b = 0; b < 4; ++b) acc[a][b] = {0.f, 0.f, 0.f, 0.f};

  for (int k0 = 0; k0 < K; k0 += 32) {
    const float* ga;
    if (MODE == 0) {
      ga = A + (size_t)gm * K + k0 + k8;
    } else if (MODE == 1) {
      int kk = k0 + k8, rg = kk >> 7, ko = kk & 127;
      if (rg == 0)      ga = s0 + (size_t)rv * DD + ko;
      else if (rg == 1) ga = s0 + (size_t)cv * DD + ko;
      else if (rg == 2) ga = s1 + (size_t)gm * DD + ko;
      else              ga = s2 + (size_t)bv * DD + ko;
    } else {
      int kk = k0 + k8, rg = kk >> 7, ko = kk & 127;
      if (rg == 0)      ga = s0 + (size_t)gm * DD + ko;
      else if (rg == 1) ga = s1 + (size_t)gm * DD + ko;
      else              ga = s2 + (size_t)bv * DD + ko;
    }
    f32x4 a0 = *(const f32x4*)ga;
    f32x4 a1 = *(const f32x4*)(ga + 4);
    bf16x8 vh, vl;
#pragma unroll
    for (int i = 0; i < 4; ++i) {
      float x = a0[i];
      bf16 h = (bf16)x;
      vh[i] = h;
      vl[i] = (bf16)(x - (float)h);
    }
#pragma unroll
    for (int i = 0; i < 4; ++i) {
      float x = a1[i];
      bf16 h = (bf16)x;
      vh[4 + i] = h;
      vl[4 + i] = (bf16)(x - (float)h);
    }
    bf16x8 bh0 = *(const bf16x8*)(Bh + (size_t)ar * K + k0 + k8);
    bf16x8 bl0 = *(const bf16x8*)(Bl + (size_t)ar * K + k0 + k8);
    bf16x8 bh1 = *(const bf16x8*)(Bh + (size_t)(ar + 128) * K + k0 + k8);
    bf16x8 bl1 = *(const bf16x8*)(Bl + (size_t)(ar + 128) * K + k0 + k8);

    __syncthreads();  // previous iteration's LDS reads done
    *(bf16x8*)&Ash[ar * 32 + k8] = vh;
    *(bf16x8*)&Asl[ar * 32 + k8] = vl;
    *(bf16x8*)&Bsh[ar * 32 + k8] = bh0;
    *(bf16x8*)&Bsl[ar * 32 + k8] = bl0;
    *(bf16x8*)&Bsh[(ar + 128) * 32 + k8] = bh1;
    *(bf16x8*)&Bsl[(ar + 128) * 32 + k8] = bl1;
    __syncthreads();  // tiles visible

    const int lr = lane & 15, q8 = (lane >> 4) * 8;
    bf16x8 afh[4], afl[4], bfh[4], bfl[4];
#pragma unroll
    for (int mi = 0; mi < 4; ++mi) {
      afh[mi] = *(const bf16x8*)&Ash[(wm * 64 + mi * 16 + lr) * 32 + q8];
      afl[mi] = *(const bf16x8*)&Asl[(wm * 64 + mi * 16 + lr) * 32 + q8];
    }
#pragma unroll
    for (int ni = 0; ni < 4; ++ni) {
      bfh[ni] = *(const bf16x8*)&Bsh[(wn * 64 + ni * 16 + lr) * 32 + q8];
      bfl[ni] = *(const bf16x8*)&Bsl[(wn * 64 + ni * 16 + lr) * 32 + q8];
    }
#pragma unroll
    for (int mi = 0; mi < 4; ++mi)
#pragma unroll
      for (int ni = 0; ni < 4; ++ni) {
        acc[mi][ni] = __builtin_amdgcn_mfma_f32_16x16x32_bf16(
            afl[mi], bfh[ni], acc[mi][ni], 0, 0, 0);
        acc[mi][ni] = __builtin_amdgcn_mfma_f32_16x16x32_bf16(
            afh[mi], bfl[ni], acc[mi][ni], 0, 0, 0);
        acc[mi][ni] = __builtin_amdgcn_mfma_f32_16x16x32_bf16(
            afh[mi], bfh[ni], acc[mi][ni], 0, 0, 0);
      }
  }

  // C/D layout: col=lane&15, row=(lane>>4)*4+reg  [measured m89/m91]
  const int lr = lane & 15;
  const int rq = (lane >> 4) * 4;
#pragma unroll
  for (int ni = 0; ni < 4; ++ni) {
    int n = wn * 64 + ni * 16 + lr;
    float bb = bias[n];
#pragma unroll
    for (int mi = 0; mi < 4; ++mi) {
#pragma unroll
      for (int r = 0; r < 4; ++r) {
        int m = m0 + wm * 64 + mi * 16 + rq + r;
        if (m < M) {
          float v = acc[mi][ni][r] + bb;
          if (do_relu) v = v > 0.f ? v : 0.f;
          C[(size_t)m * 256 + n] = v;
        }
      }
    }
  }
}

// 128x128-tile GEMM, 256 threads, plain f32 A (final N=128 layers).
__global__ __launch_bounds__(256) void gemm128(
    const float* __restrict__ A, const bf16* __restrict__ Bh,
    const bf16* __restrict__ Bl, const float* __restrict__ bias,
    float* __restrict__ C, int M, int N, int K, int do_relu) {
  __shared__ bf16 Ash[128 * 32];
  __shared__ bf16 Asl[128 * 32];
  __shared__ bf16 Bsh[128 * 32];
  __shared__ bf16 Bsl[128 * 32];
  const int tid = threadIdx.x;
  const int w = tid >> 6, lane = tid & 63;
  const int wm = w >> 1, wn = w & 1;
  const int m0 = blockIdx.x * 128, n0 = blockIdx.y * 128;
  const int ar = tid >> 2;        // 0..63: rows ar and ar+64
  const int k8 = (tid & 3) * 8;

  int gmA0 = m0 + ar;      if (gmA0 > M - 1) gmA0 = M - 1;
  int gmA1 = m0 + ar + 64; if (gmA1 > M - 1) gmA1 = M - 1;

  f32x4 acc[4][4];
#pragma unroll
  for (int a = 0; a < 4; ++a)
#pragma unroll
    for (int b = 0; b < 4; ++b) acc[a][b] = {0.f, 0.f, 0.f, 0.f};

  for (int k0 = 0; k0 < K; k0 += 32) {
    f32x4 a00 = *(const f32x4*)(A + (size_t)gmA0 * K + k0 + k8);
    f32x4 a01 = *(const f32x4*)(A + (size_t)gmA0 * K + k0 + k8 + 4);
    f32x4 a10 = *(const f32x4*)(A + (size_t)gmA1 * K + k0 + k8);
    f32x4 a11 = *(const f32x4*)(A + (size_t)gmA1 * K + k0 + k8 + 4);
    bf16x8 v0h, v0l, v1h, v1l;
#pragma unroll
    for (int i = 0; i < 4; ++i) {
      float x = a00[i]; bf16 h = (bf16)x; v0h[i] = h; v0l[i] = (bf16)(x - (float)h);
      x = a01[i]; h = (bf16)x; v0h[4 + i] = h; v0l[4 + i] = (bf16)(x - (float)h);
      x = a10[i]; h = (bf16)x; v1h[i] = h; v1l[i] = (bf16)(x - (float)h);
      x = a11[i]; h = (bf16)x; v1h[4 + i] = h; v1l[4 + i] = (bf16)(x - (float)h);
    }
    bf16x8 bh0 = *(const bf16x8*)(Bh + (size_t)(n0 + ar) * K + k0 + k8);
    bf16x8 bl0 = *(const bf16x8*)(Bl + (size_t)(n0 + ar) * K + k0 + k8);
    bf16x8 bh1 = *(const bf16x8*)(Bh + (size_t)(n0 + ar + 64) * K + k0 + k8);
    bf16x8 bl1 = *(const bf16x8*)(Bl + (size_t)(n0 + ar + 64) * K + k0 + k8);

    __syncthreads();
    *(bf16x8*)&Ash[ar * 32 + k8] = v0h;
    *(bf16x8*)&Asl[ar * 32 + k8] = v0l;
    *(bf16x8*)&Ash[(ar + 64) * 32 + k8] = v1h;
    *(bf16x8*)&Asl[(ar + 64) * 32 + k8] = v1l;
    *(bf16x8*)&Bsh[ar * 32 + k8] = bh0;
    *(bf16x8*)&Bsl[ar * 32 + k8] = bl0;
    *(bf16x8*)&Bsh[(ar + 64) * 32 + k8] = bh1;
    *(bf16x8*)&Bsl[(ar + 64) * 32 + k8] = bl1;
    __syncthreads();

    const int lr = lane & 15, q8 = (lane >> 4) * 8;
    bf16x8 afh[4], afl[4], bfh[4], bfl[4];
#pragma unroll
    for (int mi = 0; mi < 4; ++mi) {
      afh[mi] = *(const bf16x8*)&Ash[(wm * 64 + mi * 16 + lr) * 32 + q8];
      afl[mi] = *(const bf16x8*)&Asl[(wm * 64 + mi * 16 + lr) * 32 + q8];
    }
#pragma unroll
    for (int ni = 0; ni < 4; ++ni) {
      bfh[ni] = *(const bf16x8*)&Bsh[(wn * 64 + ni * 16 + lr) * 32 + q8];
      bfl[ni] = *(const bf16x8*)&Bsl[(wn * 64 + ni * 16 + lr) * 32 + q8];
    }
#pragma unroll
    for (int mi = 0; mi < 4; ++mi)
#pragma unroll
      for (int ni = 0; ni < 4; ++ni) {
        acc[mi][ni] = __builtin_amdgcn_mfma_f32_16x16x32_bf16(
            afl[mi], bfh[ni], acc[mi][ni], 0, 0, 0);
        acc[mi][ni] = __builtin_amdgcn_mfma_f32_16x16x32_bf16(
            afh[mi], bfl[ni], acc[mi][ni], 0, 0, 0);
        acc[mi][ni] = __builtin_amdgcn_mfma_f32_16x16x32_bf16(
            afh[mi], bfh[ni], acc[mi][ni], 0, 0, 0);
      }
  }

  const int lr = lane & 15;
  const int rq = (lane >> 4) * 4;
#pragma unroll
  for (int ni = 0; ni < 4; ++ni) {
    int n = n0 + wn * 64 + ni * 16 + lr;
    float bb = bias[n];
#pragma unroll
    for (int mi = 0; mi < 4; ++mi) {
#pragma unroll
      for (int r = 0; r < 4; ++r) {
        int m = m0 + wm * 64 + mi * 16 + rq + r;
        if (m < M) {
          float v = acc[mi][ni][r] + bb;
          if (do_relu) v = v > 0.f ? v : 0.f;
          C[(size_t)m * N + n] = v;
        }
      }
    }
  }
}

// Split W[K,N] f32 into transposed hi/lo bf16 [N,K].
__global__ void splitw_k(const float* __restrict__ W, bf16* __restrict__ Wh,
                         bf16* __restrict__ Wl, int K, int N) {
  int i = blockIdx.x * 256 + threadIdx.x;
  if (i < K * N) {
    int k = i / N, n = i % N;
    float x = W[i];
    bf16 h = (bf16)x;
    Wh[(size_t)n * K + k] = h;
    Wl[(size_t)n * K + k] = (bf16)(x - (float)h);
  }
}

__global__ void agg_edges_k(const float* __restrict__ eout,
                            const int* __restrict__ row,
                            const int* __restrict__ col,
                            const int* __restrict__ batch,
                            float* __restrict__ agg_sum,
                            float* __restrict__ cnt_node,
                            float* __restrict__ egsum,
                            float* __restrict__ cnt_ge) {
  int e = blockIdx.x;
  int d = threadIdx.x;  // 128 threads, one per feature dim
  int c = col[e];
  int g = batch[row[e]];
  float v = eout[(size_t)e * 128 + d];
  atomicAdd(&agg_sum[(size_t)c * 128 + d], v);
  atomicAdd(&egsum[((size_t)(e & 63) * 128 + g) * 128 + d], v);
  if (d == 0) {
    atomicAdd(&cnt_node[c], 1.f);
    atomicAdd(&cnt_ge[g], 1.f);
  }
}

// In-place: agg_sum -> mean
__global__ void agg_fin_k(float* __restrict__ agg_sum,
                          const float* __restrict__ cnt_node) {
  int i = blockIdx.x * 256 + threadIdx.x;
  if (i < NN * 128) {
    float c = cnt_node[i >> 7];
    c = c > 1.f ? c : 1.f;
    agg_sum[i] = agg_sum[i] / c;
  }
}

__global__ void node_gagg_k(const float* __restrict__ nout,
                            const int* __restrict__ batch,
                            float* __restrict__ ngsum,
                            float* __restrict__ cnt_gn) {
  int n = blockIdx.x, d = threadIdx.x;
  int g = batch[n];
  float v = nout[(size_t)n * 128 + d];
  atomicAdd(&ngsum[((size_t)(n & 63) * 128 + g) * 128 + d], v);
  if (d == 0) atomicAdd(&cnt_gn[g], 1.f);
}

__global__ void gin_k(const float* __restrict__ ngsum,
                      const float* __restrict__ egsum,
                      const float* __restrict__ cnt_gn,
                      const float* __restrict__ cnt_ge,
                      const float* __restrict__ u, float* __restrict__ g_in) {
  int g = blockIdx.x, d = threadIdx.x;
  float ns = 0.f, es = 0.f;
  for (int r = 0; r < 64; ++r) {
    ns += ngsum[((size_t)r * 128 + g) * 128 + d];
    es += egsum[((size_t)r * 128 + g) * 128 + d];
  }
  float cn = cnt_gn[g]; cn = cn > 1.f ? cn : 1.f;
  float ce = cnt_ge[g]; ce = ce > 1.f ? ce : 1.f;
  g_in[g * 384 + d] = u[g * 128 + d];
  g_in[g * 384 + 128 + d] = ns / cn;
  g_in[g * 384 + 256 + d] = es / ce;
}

extern "C" void kernel_launch(void* const* d_in, const int* in_sizes, int n_in,
                              void* d_out, int out_size, void* d_ws,
                              size_t ws_size, hipStream_t stream) {
  (void)in_sizes; (void)n_in; (void)out_size; (void)ws_size;
  const float* nodes = (const float*)d_in[0];
  const int* eidx = (const int*)d_in[1];
  const float* eattr = (const float*)d_in[2];
  const float* u = (const float*)d_in[3];
  const int* batch = (const int*)d_in[4];
  const float* W[9] = {(const float*)d_in[5],  (const float*)d_in[7],
                       (const float*)d_in[9],  (const float*)d_in[11],
                       (const float*)d_in[13], (const float*)d_in[15],
                       (const float*)d_in[17], (const float*)d_in[19],
                       (const float*)d_in[21]};
  const float* Bi[9] = {(const float*)d_in[6],  (const float*)d_in[8],
                        (const float*)d_in[10], (const float*)d_in[12],
                        (const float*)d_in[14], (const float*)d_in[16],
                        (const float*)d_in[18], (const float*)d_in[20],
                        (const float*)d_in[22]};
  const int* row = eidx;
  const int* col = eidx + NE;

  char* p = (char*)d_ws;
  auto alloc = [&](size_t b) {
    void* r = (void*)p;
    p += (b + 255) & ~(size_t)255;
    return r;
  };
  float* h_e0 = (float*)alloc((size_t)NE * 256 * 4);  // f32 hidden, in-place L1
  const int wk[9] = {512, 256, 256, 384, 256, 256, 384, 256, 256};
  const int wn[9] = {256, 256, 128, 256, 256, 128, 256, 256, 128};
  bf16 *Wh[9], *Wl[9];
  for (int i = 0; i < 9; ++i) {
    Wh[i] = (bf16*)alloc((size_t)wk[i] * wn[i] * 2);
    Wl[i] = (bf16*)alloc((size_t)wk[i] * wn[i] * 2);
  }
  char* zero_base = p;
  float* agg_sum = (float*)alloc((size_t)NN * 128 * 4);
  float* cnt_node = (float*)alloc((size_t)NN * 4);
  float* ngsum = (float*)alloc((size_t)64 * 128 * 128 * 4);
  float* egsum = (float*)alloc((size_t)64 * 128 * 128 * 4);
  float* cnt_gn = (float*)alloc(512);
  float* cnt_ge = (float*)alloc(512);
  size_t zero_len = (size_t)(p - zero_base);
  float* g_in = (float*)alloc((size_t)NG * 384 * 4);
  float* h_g0 = (float*)alloc((size_t)NG * 256 * 4);
  float* h_n0 = h_e0;  // edge hidden dead by node-MLP time

  float* out_nodes = (float*)d_out;
  float* out_edges = out_nodes + (size_t)NN * 128;
  float* out_glob = out_nodes + (size_t)NN * 128 + (size_t)NE * 128;

  for (int i = 0; i < 9; ++i) {
    int tot = wk[i] * wn[i];
    splitw_k<<<(tot + 255) / 256, 256, 0, stream>>>(W[i], Wh[i], Wl[i], wk[i],
                                                    wn[i]);
  }
  hipMemsetAsync(zero_base, 0, zero_len, stream);

  const int gbE = (NE + 127) / 128;   // 2344
  const int gbN = (NN + 127) / 128;   // 235

  // Edge MLP: 512 -> 256 -> 256 -> 128
  gemm_wide<1><<<gbE, 512, 0, stream>>>(nullptr, Wh[0], Wl[0], Bi[0], h_e0, NE,
                                        512, 1, nodes, eattr, u, row, col,
                                        batch);
  gemm_wide<0><<<gbE, 512, 0, stream>>>(h_e0, Wh[1], Wl[1], Bi[1], h_e0, NE,
                                        256, 1, nullptr, nullptr, nullptr,
                                        nullptr, nullptr, nullptr);
  gemm128<<<dim3(gbE, 1), 256, 0, stream>>>(h_e0, Wh[2], Wl[2], Bi[2],
                                            out_edges, NE, 128, 256, 0);

  agg_edges_k<<<NE, 128, 0, stream>>>(out_edges, row, col, batch, agg_sum,
                                      cnt_node, egsum, cnt_ge);
  agg_fin_k<<<(NN * 128 + 255) / 256, 256, 0, stream>>>(agg_sum, cnt_node);

  // Node MLP: 384 -> 256 -> 256 -> 128
  gemm_wide<2><<<gbN, 512, 0, stream>>>(nullptr, Wh[3], Wl[3], Bi[3], h_n0, NN,
                                        384, 1, nodes, agg_sum, u, nullptr,
                                        nullptr, batch);
  gemm_wide<0><<<gbN, 512, 0, stream>>>(h_n0, Wh[4], Wl[4], Bi[4], h_n0, NN,
                                        256, 1, nullptr, nullptr, nullptr,
                                        nullptr, nullptr, nullptr);
  gemm128<<<dim3(gbN, 1), 256, 0, stream>>>(h_n0, Wh[5], Wl[5], Bi[5],
                                            out_nodes, NN, 128, 256, 0);

  node_gagg_k<<<NN, 128, 0, stream>>>(out_nodes, batch, ngsum, cnt_gn);
  gin_k<<<NG, 128, 0, stream>>>(ngsum, egsum, cnt_gn, cnt_ge, u, g_in);

  // Global MLP: 384 -> 256 -> 256 -> 128
  gemm_wide<0><<<1, 512, 0, stream>>>(g_in, Wh[6], Wl[6], Bi[6], h_g0, NG, 384,
                                      1, nullptr, nullptr, nullptr, nullptr,
                                      nullptr, nullptr);
  gemm_wide<0><<<1, 512, 0, stream>>>(h_g0, Wh[7], Wl[7], Bi[7], h_g0, NG, 256,
                                      1, nullptr, nullptr, nullptr, nullptr,
                                      nullptr, nullptr);
  gemm128<<<dim3(1, 1), 256, 0, stream>>>(h_g0, Wh[8], Wl[8], Bi[8], out_glob,
                                          NG, 128, 256, 0);
}

// Round 4
// 1665.802 us; speedup vs baseline: 1.5504x; 1.5504x over previous
//
#include <hip/hip_runtime.h>
#include <stdint.h>

typedef __bf16 bf16;
typedef __bf16 bf16x8 __attribute__((ext_vector_type(8)));
typedef float f32x4 __attribute__((ext_vector_type(4)));

#define NN 30000
#define NE 300000
#define NG 128
#define DD 128

// ---------------------------------------------------------------------------
// f32-accurate GEMM via 3-term bf16 split: a*b ~= ah*bh + ah*bl + al*bh.
// ---------------------------------------------------------------------------
template <int MODE>
__global__ __launch_bounds__(512) void gemm_wide(
    const float* __restrict__ A, const bf16* __restrict__ Bh,
    const bf16* __restrict__ Bl, const float* __restrict__ bias,
    float* __restrict__ C, int M, int K, int do_relu,
    const float* __restrict__ s0, const float* __restrict__ s1,
    const float* __restrict__ s2, const int* __restrict__ i0,
    const int* __restrict__ i1, const int* __restrict__ i2) {
  __shared__ bf16 Ash[128 * 32];
  __shared__ bf16 Asl[128 * 32];
  __shared__ bf16 Bsh[256 * 32];
  __shared__ bf16 Bsl[256 * 32];
  const int tid = threadIdx.x;
  const int w = tid >> 6, lane = tid & 63;
  const int wm = w >> 2, wn = w & 3;  // 2 x 4 waves over 128 x 256
  const int m0 = blockIdx.x * 128;
  const int ar = tid >> 2;        // 0..127: A row / B row pair
  const int k8 = (tid & 3) * 8;   // 0,8,16,24 within 32-wide k-slab

  int gm = m0 + ar;
  if (gm > M - 1) gm = M - 1;  // clamp partial tile; stores guarded below
  int rv = 0, cv = 0, bv = 0;
  if (MODE == 1) {
    rv = i0[gm];
    cv = i1[gm];
    bv = i2[rv];
  } else if (MODE == 2) {
    bv = i2[gm];
  }

  f32x4 acc[4][4];
#pragma unroll
  for (int a = 0; a < 4; ++a)
#pragma unroll
    for (int b = 0; b < 4; ++b) acc[a][b] = {0.f, 0.f, 0.f, 0.f};

  for (int k0 = 0; k0 < K; k0 += 32) {
    const float* ga;
    if (MODE == 0) {
      ga = A + (size_t)gm * K + k0 + k8;
    } else if (MODE == 1) {
      int kk = k0 + k8, rg = kk >> 7, ko = kk & 127;
      if (rg == 0)      ga = s0 + (size_t)rv * DD + ko;
      else if (rg == 1) ga = s0 + (size_t)cv * DD + ko;
      else if (rg == 2) ga = s1 + (size_t)gm * DD + ko;
      else              ga = s2 + (size_t)bv * DD + ko;
    } else {
      int kk = k0 + k8, rg = kk >> 7, ko = kk & 127;
      if (rg == 0)      ga = s0 + (size_t)gm * DD + ko;
      else if (rg == 1) ga = s1 + (size_t)gm * DD + ko;
      else              ga = s2 + (size_t)bv * DD + ko;
    }
    f32x4 a0 = *(const f32x4*)ga;
    f32x4 a1 = *(const f32x4*)(ga + 4);
    bf16x8 vh, vl;
#pragma unroll
    for (int i = 0; i < 4; ++i) {
      float x = a0[i];
      bf16 h = (bf16)x;
      vh[i] = h;
      vl[i] = (bf16)(x - (float)h);
    }
#pragma unroll
    for (int i = 0; i < 4; ++i) {
      float x = a1[i];
      bf16 h = (bf16)x;
      vh[4 + i] = h;
      vl[4 + i] = (bf16)(x - (float)h);
    }
    bf16x8 bh0 = *(const bf16x8*)(Bh + (size_t)ar * K + k0 + k8);
    bf16x8 bl0 = *(const bf16x8*)(Bl + (size_t)ar * K + k0 + k8);
    bf16x8 bh1 = *(const bf16x8*)(Bh + (size_t)(ar + 128) * K + k0 + k8);
    bf16x8 bl1 = *(const bf16x8*)(Bl + (size_t)(ar + 128) * K + k0 + k8);

    __syncthreads();
    *(bf16x8*)&Ash[ar * 32 + k8] = vh;
    *(bf16x8*)&Asl[ar * 32 + k8] = vl;
    *(bf16x8*)&Bsh[ar * 32 + k8] = bh0;
    *(bf16x8*)&Bsl[ar * 32 + k8] = bl0;
    *(bf16x8*)&Bsh[(ar + 128) * 32 + k8] = bh1;
    *(bf16x8*)&Bsl[(ar + 128) * 32 + k8] = bl1;
    __syncthreads();

    const int lr = lane & 15, q8 = (lane >> 4) * 8;
    bf16x8 afh[4], afl[4], bfh[4], bfl[4];
#pragma unroll
    for (int mi = 0; mi < 4; ++mi) {
      afh[mi] = *(const bf16x8*)&Ash[(wm * 64 + mi * 16 + lr) * 32 + q8];
      afl[mi] = *(const bf16x8*)&Asl[(wm * 64 + mi * 16 + lr) * 32 + q8];
    }
#pragma unroll
    for (int ni = 0; ni < 4; ++ni) {
      bfh[ni] = *(const bf16x8*)&Bsh[(wn * 64 + ni * 16 + lr) * 32 + q8];
      bfl[ni] = *(const bf16x8*)&Bsl[(wn * 64 + ni * 16 + lr) * 32 + q8];
    }
#pragma unroll
    for (int mi = 0; mi < 4; ++mi)
#pragma unroll
      for (int ni = 0; ni < 4; ++ni) {
        acc[mi][ni] = __builtin_amdgcn_mfma_f32_16x16x32_bf16(
            afl[mi], bfh[ni], acc[mi][ni], 0, 0, 0);
        acc[mi][ni] = __builtin_amdgcn_mfma_f32_16x16x32_bf16(
            afh[mi], bfl[ni], acc[mi][ni], 0, 0, 0);
        acc[mi][ni] = __builtin_amdgcn_mfma_f32_16x16x32_bf16(
            afh[mi], bfh[ni], acc[mi][ni], 0, 0, 0);
      }
  }

  // C/D layout: col=lane&15, row=(lane>>4)*4+reg  [measured m89/m91]
  const int lr = lane & 15;
  const int rq = (lane >> 4) * 4;
#pragma unroll
  for (int ni = 0; ni < 4; ++ni) {
    int n = wn * 64 + ni * 16 + lr;
    float bb = bias[n];
#pragma unroll
    for (int mi = 0; mi < 4; ++mi) {
#pragma unroll
      for (int r = 0; r < 4; ++r) {
        int m = m0 + wm * 64 + mi * 16 + rq + r;
        if (m < M) {
          float v = acc[mi][ni][r] + bb;
          if (do_relu) v = v > 0.f ? v : 0.f;
          C[(size_t)m * 256 + n] = v;
        }
      }
    }
  }
}

// 128x128-tile GEMM, 256 threads, plain f32 A (final N=128 layers).
__global__ __launch_bounds__(256) void gemm128(
    const float* __restrict__ A, const bf16* __restrict__ Bh,
    const bf16* __restrict__ Bl, const float* __restrict__ bias,
    float* __restrict__ C, int M, int N, int K, int do_relu) {
  __shared__ bf16 Ash[128 * 32];
  __shared__ bf16 Asl[128 * 32];
  __shared__ bf16 Bsh[128 * 32];
  __shared__ bf16 Bsl[128 * 32];
  const int tid = threadIdx.x;
  const int w = tid >> 6, lane = tid & 63;
  const int wm = w >> 1, wn = w & 1;
  const int m0 = blockIdx.x * 128, n0 = blockIdx.y * 128;
  const int ar = tid >> 2;
  const int k8 = (tid & 3) * 8;

  int gmA0 = m0 + ar;      if (gmA0 > M - 1) gmA0 = M - 1;
  int gmA1 = m0 + ar + 64; if (gmA1 > M - 1) gmA1 = M - 1;

  f32x4 acc[4][4];
#pragma unroll
  for (int a = 0; a < 4; ++a)
#pragma unroll
    for (int b = 0; b < 4; ++b) acc[a][b] = {0.f, 0.f, 0.f, 0.f};

  for (int k0 = 0; k0 < K; k0 += 32) {
    f32x4 a00 = *(const f32x4*)(A + (size_t)gmA0 * K + k0 + k8);
    f32x4 a01 = *(const f32x4*)(A + (size_t)gmA0 * K + k0 + k8 + 4);
    f32x4 a10 = *(const f32x4*)(A + (size_t)gmA1 * K + k0 + k8);
    f32x4 a11 = *(const f32x4*)(A + (size_t)gmA1 * K + k0 + k8 + 4);
    bf16x8 v0h, v0l, v1h, v1l;
#pragma unroll
    for (int i = 0; i < 4; ++i) {
      float x = a00[i]; bf16 h = (bf16)x; v0h[i] = h; v0l[i] = (bf16)(x - (float)h);
      x = a01[i]; h = (bf16)x; v0h[4 + i] = h; v0l[4 + i] = (bf16)(x - (float)h);
      x = a10[i]; h = (bf16)x; v1h[i] = h; v1l[i] = (bf16)(x - (float)h);
      x = a11[i]; h = (bf16)x; v1h[4 + i] = h; v1l[4 + i] = (bf16)(x - (float)h);
    }
    bf16x8 bh0 = *(const bf16x8*)(Bh + (size_t)(n0 + ar) * K + k0 + k8);
    bf16x8 bl0 = *(const bf16x8*)(Bl + (size_t)(n0 + ar) * K + k0 + k8);
    bf16x8 bh1 = *(const bf16x8*)(Bh + (size_t)(n0 + ar + 64) * K + k0 + k8);
    bf16x8 bl1 = *(const bf16x8*)(Bl + (size_t)(n0 + ar + 64) * K + k0 + k8);

    __syncthreads();
    *(bf16x8*)&Ash[ar * 32 + k8] = v0h;
    *(bf16x8*)&Asl[ar * 32 + k8] = v0l;
    *(bf16x8*)&Ash[(ar + 64) * 32 + k8] = v1h;
    *(bf16x8*)&Asl[(ar + 64) * 32 + k8] = v1l;
    *(bf16x8*)&Bsh[ar * 32 + k8] = bh0;
    *(bf16x8*)&Bsl[ar * 32 + k8] = bl0;
    *(bf16x8*)&Bsh[(ar + 64) * 32 + k8] = bh1;
    *(bf16x8*)&Bsl[(ar + 64) * 32 + k8] = bl1;
    __syncthreads();

    const int lr = lane & 15, q8 = (lane >> 4) * 8;
    bf16x8 afh[4], afl[4], bfh[4], bfl[4];
#pragma unroll
    for (int mi = 0; mi < 4; ++mi) {
      afh[mi] = *(const bf16x8*)&Ash[(wm * 64 + mi * 16 + lr) * 32 + q8];
      afl[mi] = *(const bf16x8*)&Asl[(wm * 64 + mi * 16 + lr) * 32 + q8];
    }
#pragma unroll
    for (int ni = 0; ni < 4; ++ni) {
      bfh[ni] = *(const bf16x8*)&Bsh[(wn * 64 + ni * 16 + lr) * 32 + q8];
      bfl[ni] = *(const bf16x8*)&Bsl[(wn * 64 + ni * 16 + lr) * 32 + q8];
    }
#pragma unroll
    for (int mi = 0; mi < 4; ++mi)
#pragma unroll
      for (int ni = 0; ni < 4; ++ni) {
        acc[mi][ni] = __builtin_amdgcn_mfma_f32_16x16x32_bf16(
            afl[mi], bfh[ni], acc[mi][ni], 0, 0, 0);
        acc[mi][ni] = __builtin_amdgcn_mfma_f32_16x16x32_bf16(
            afh[mi], bfl[ni], acc[mi][ni], 0, 0, 0);
        acc[mi][ni] = __builtin_amdgcn_mfma_f32_16x16x32_bf16(
            afh[mi], bfh[ni], acc[mi][ni], 0, 0, 0);
      }
  }

  const int lr = lane & 15;
  const int rq = (lane >> 4) * 4;
#pragma unroll
  for (int ni = 0; ni < 4; ++ni) {
    int n = n0 + wn * 64 + ni * 16 + lr;
    float bb = bias[n];
#pragma unroll
    for (int mi = 0; mi < 4; ++mi) {
#pragma unroll
      for (int r = 0; r < 4; ++r) {
        int m = m0 + wm * 64 + mi * 16 + rq + r;
        if (m < M) {
          float v = acc[mi][ni][r] + bb;
          if (do_relu) v = v > 0.f ? v : 0.f;
          C[(size_t)m * N + n] = v;
        }
      }
    }
  }
}

__global__ void splitw_k(const float* __restrict__ W, bf16* __restrict__ Wh,
                         bf16* __restrict__ Wl, int K, int N) {
  int i = blockIdx.x * 256 + threadIdx.x;
  if (i < K * N) {
    int k = i / N, n = i % N;
    float x = W[i];
    bf16 h = (bf16)x;
    Wh[(size_t)n * K + k] = h;
    Wl[(size_t)n * K + k] = (bf16)(x - (float)h);
  }
}

// ---------------------------------------------------------------------------
// Aggregation, contention-split:
//  - agg_scatter_k: node-level scatter (benign ~10-way contention) as plain
//    global atomics, PLUS per-graph edge sums staged in an LDS histogram
//    (contended part) with one flush atomic per (graph,dim) per block.
//    Block = 256 threads, owns (1024-edge chunk) x (64-dim half).
//    LDS layout part[g*64+dd]: bank = dd%32 = lane%32 -> conflict-free.
// ---------------------------------------------------------------------------
#define CHUNK 1024
__global__ __launch_bounds__(256) void agg_scatter_k(
    const float* __restrict__ eout, const int* __restrict__ row,
    const int* __restrict__ col, const int* __restrict__ batch,
    float* __restrict__ agg_sum, float* __restrict__ eg_final) {
  __shared__ float part[NG * 64];  // 32 KB
  const int tid = threadIdx.x;
  const int dg = blockIdx.y;        // dim half: 0 or 1
  const int base = blockIdx.x * CHUNK;
  for (int i = tid; i < NG * 64; i += 256) part[i] = 0.f;
  __syncthreads();

  const int es = tid >> 5;        // 0..7: edge sub-index within iter
  const int dl = tid & 31;        // dim lane
  for (int it = 0; it < CHUNK / 8; ++it) {
    int e = base + it * 8 + es;
    if (e < NE) {
      int c = col[e];
      int g = batch[row[e]];
      const float* ep = eout + (size_t)e * 128 + dg * 64 + dl;
      float v0 = ep[0];
      float v1 = ep[32];
      atomicAdd(&agg_sum[(size_t)c * 128 + dg * 64 + dl], v0);
      atomicAdd(&agg_sum[(size_t)c * 128 + dg * 64 + dl + 32], v1);
      atomicAdd(&part[g * 64 + dl], v0);
      atomicAdd(&part[g * 64 + dl + 32], v1);
    }
  }
  __syncthreads();
  for (int i = tid; i < NG * 64; i += 256) {
    int g = i >> 6, dd = i & 63;
    atomicAdd(&eg_final[g * 128 + dg * 64 + dd], part[i]);
  }
}

// Counts: cnt_node (10-way avg, global atomics) + cnt_ge (high contention,
// LDS histogram per block, one flush atomic per graph per block).
__global__ __launch_bounds__(256) void cnt_k(const int* __restrict__ row,
                                             const int* __restrict__ col,
                                             const int* __restrict__ batch,
                                             float* __restrict__ cnt_node,
                                             float* __restrict__ cnt_ge) {
  __shared__ float hist[NG];
  const int tid = threadIdx.x;
  if (tid < NG) hist[tid] = 0.f;
  __syncthreads();
  for (int e = blockIdx.x * 256 + tid; e < NE; e += gridDim.x * 256) {
    atomicAdd(&cnt_node[col[e]], 1.f);
    atomicAdd(&hist[batch[row[e]]], 1.f);
  }
  __syncthreads();
  if (tid < NG) atomicAdd(&cnt_ge[tid], hist[tid]);
}

// In-place: agg_sum -> mean
__global__ void agg_fin_k(float* __restrict__ agg_sum,
                          const float* __restrict__ cnt_node) {
  int i = blockIdx.x * 256 + threadIdx.x;
  if (i < NN * 128) {
    float c = cnt_node[i >> 7];
    c = c > 1.f ? c : 1.f;
    agg_sum[i] = agg_sum[i] / c;
  }
}

__global__ void node_gagg_k(const float* __restrict__ nout,
                            const int* __restrict__ batch,
                            float* __restrict__ ngsum,
                            float* __restrict__ cnt_gn) {
  int n = blockIdx.x, d = threadIdx.x;
  int g = batch[n];
  float v = nout[(size_t)n * 128 + d];
  atomicAdd(&ngsum[((size_t)(n & 63) * 128 + g) * 128 + d], v);
  if (d == 0) atomicAdd(&cnt_gn[g], 1.f);
}

__global__ void gin_k(const float* __restrict__ ngsum,
                      const float* __restrict__ eg_final,
                      const float* __restrict__ cnt_gn,
                      const float* __restrict__ cnt_ge,
                      const float* __restrict__ u, float* __restrict__ g_in) {
  int g = blockIdx.x, d = threadIdx.x;
  float ns = 0.f;
  for (int r = 0; r < 64; ++r) ns += ngsum[((size_t)r * 128 + g) * 128 + d];
  float es = eg_final[g * 128 + d];
  float cn = cnt_gn[g]; cn = cn > 1.f ? cn : 1.f;
  float ce = cnt_ge[g]; ce = ce > 1.f ? ce : 1.f;
  g_in[g * 384 + d] = u[g * 128 + d];
  g_in[g * 384 + 128 + d] = ns / cn;
  g_in[g * 384 + 256 + d] = es / ce;
}

extern "C" void kernel_launch(void* const* d_in, const int* in_sizes, int n_in,
                              void* d_out, int out_size, void* d_ws,
                              size_t ws_size, hipStream_t stream) {
  (void)in_sizes; (void)n_in; (void)out_size; (void)ws_size;
  const float* nodes = (const float*)d_in[0];
  const int* eidx = (const int*)d_in[1];
  const float* eattr = (const float*)d_in[2];
  const float* u = (const float*)d_in[3];
  const int* batch = (const int*)d_in[4];
  const float* W[9] = {(const float*)d_in[5],  (const float*)d_in[7],
                       (const float*)d_in[9],  (const float*)d_in[11],
                       (const float*)d_in[13], (const float*)d_in[15],
                       (const float*)d_in[17], (const float*)d_in[19],
                       (const float*)d_in[21]};
  const float* Bi[9] = {(const float*)d_in[6],  (const float*)d_in[8],
                        (const float*)d_in[10], (const float*)d_in[12],
                        (const float*)d_in[14], (const float*)d_in[16],
                        (const float*)d_in[18], (const float*)d_in[20],
                        (const float*)d_in[22]};
  const int* row = eidx;
  const int* col = eidx + NE;

  char* p = (char*)d_ws;
  auto alloc = [&](size_t b) {
    void* r = (void*)p;
    p += (b + 255) & ~(size_t)255;
    return r;
  };
  float* h_e0 = (float*)alloc((size_t)NE * 256 * 4);  // f32 hidden, in-place L1
  const int wk[9] = {512, 256, 256, 384, 256, 256, 384, 256, 256};
  const int wn[9] = {256, 256, 128, 256, 256, 128, 256, 256, 128};
  bf16 *Wh[9], *Wl[9];
  for (int i = 0; i < 9; ++i) {
    Wh[i] = (bf16*)alloc((size_t)wk[i] * wn[i] * 2);
    Wl[i] = (bf16*)alloc((size_t)wk[i] * wn[i] * 2);
  }
  char* zero_base = p;
  float* agg_sum = (float*)alloc((size_t)NN * 128 * 4);
  float* cnt_node = (float*)alloc((size_t)NN * 4);
  float* ngsum = (float*)alloc((size_t)64 * 128 * 128 * 4);
  float* eg_final = (float*)alloc((size_t)NG * 128 * 4);
  float* cnt_gn = (float*)alloc(512);
  float* cnt_ge = (float*)alloc(512);
  size_t zero_len = (size_t)(p - zero_base);
  float* g_in = (float*)alloc((size_t)NG * 384 * 4);
  float* h_g0 = (float*)alloc((size_t)NG * 256 * 4);
  float* h_n0 = h_e0;

  float* out_nodes = (float*)d_out;
  float* out_edges = out_nodes + (size_t)NN * 128;
  float* out_glob = out_nodes + (size_t)NN * 128 + (size_t)NE * 128;

  for (int i = 0; i < 9; ++i) {
    int tot = wk[i] * wn[i];
    splitw_k<<<(tot + 255) / 256, 256, 0, stream>>>(W[i], Wh[i], Wl[i], wk[i],
                                                    wn[i]);
  }
  hipMemsetAsync(zero_base, 0, zero_len, stream);

  const int gbE = (NE + 127) / 128;   // 2344
  const int gbN = (NN + 127) / 128;   // 235

  // Edge MLP: 512 -> 256 -> 256 -> 128
  gemm_wide<1><<<gbE, 512, 0, stream>>>(nullptr, Wh[0], Wl[0], Bi[0], h_e0, NE,
                                        512, 1, nodes, eattr, u, row, col,
                                        batch);
  gemm_wide<0><<<gbE, 512, 0, stream>>>(h_e0, Wh[1], Wl[1], Bi[1], h_e0, NE,
                                        256, 1, nullptr, nullptr, nullptr,
                                        nullptr, nullptr, nullptr);
  gemm128<<<dim3(gbE, 1), 256, 0, stream>>>(h_e0, Wh[2], Wl[2], Bi[2],
                                            out_edges, NE, 128, 256, 0);

  // Aggregations (contention-split)
  agg_scatter_k<<<dim3((NE + CHUNK - 1) / CHUNK, 2), 256, 0, stream>>>(
      out_edges, row, col, batch, agg_sum, eg_final);
  cnt_k<<<128, 256, 0, stream>>>(row, col, batch, cnt_node, cnt_ge);
  agg_fin_k<<<(NN * 128 + 255) / 256, 256, 0, stream>>>(agg_sum, cnt_node);

  // Node MLP: 384 -> 256 -> 256 -> 128
  gemm_wide<2><<<gbN, 512, 0, stream>>>(nullptr, Wh[3], Wl[3], Bi[3], h_n0, NN,
                                        384, 1, nodes, agg_sum, u, nullptr,
                                        nullptr, batch);
  gemm_wide<0><<<gbN, 512, 0, stream>>>(h_n0, Wh[4], Wl[4], Bi[4], h_n0, NN,
                                        256, 1, nullptr, nullptr, nullptr,
                                        nullptr, nullptr, nullptr);
  gemm128<<<dim3(gbN, 1), 256, 0, stream>>>(h_n0, Wh[5], Wl[5], Bi[5],
                                            out_nodes, NN, 128, 256, 0);

  node_gagg_k<<<NN, 128, 0, stream>>>(out_nodes, batch, ngsum, cnt_gn);
  gin_k<<<NG, 128, 0, stream>>>(ngsum, eg_final, cnt_gn, cnt_ge, u, g_in);

  // Global MLP: 384 -> 256 -> 256 -> 128
  gemm_wide<0><<<1, 512, 0, stream>>>(g_in, Wh[6], Wl[6], Bi[6], h_g0, NG, 384,
                                      1, nullptr, nullptr, nullptr, nullptr,
                                      nullptr, nullptr);
  gemm_wide<0><<<1, 512, 0, stream>>>(h_g0, Wh[7], Wl[7], Bi[7], h_g0, NG, 256,
                                      1, nullptr, nullptr, nullptr, nullptr,
                                      nullptr, nullptr);
  gemm128<<<dim3(1, 1), 256, 0, stream>>>(h_g0, Wh[8], Wl[8], Bi[8], out_glob,
                                          NG, 128, 256, 0);
}